// Round 1
// baseline (575.811 us; speedup 1.0000x reference)
//
#include <hip/hip_runtime.h>
#include <hip/hip_bf16.h>

// Householder reflection, row-wise over [B=16384, L=4096] fp32:
//   out[b, :] = z[b, :] - 2 * v[b, :] * (v[b]·z[b]) / (v[b]·v[b])
//
// HBM-bound: 3 arrays × 256 MiB = 768 MiB min traffic → ~128 µs at 6.3 TB/s.
// One block per row; each thread holds its 16 v / 16 z elements in registers
// across the reduction so v and z are read from HBM exactly once.

#define L 4096
#define BLOCK 256
#define VEC_PER_THREAD (L / (BLOCK * 4))  // 4 float4 per thread

__global__ __launch_bounds__(BLOCK) void hh_kernel(
    const float* __restrict__ v,
    const float* __restrict__ z,
    float* __restrict__ out)
{
    const int b   = blockIdx.x;
    const int tid = threadIdx.x;
    const long long base = (long long)b * L;

    const float4* v4 = reinterpret_cast<const float4*>(v + base);
    const float4* z4 = reinterpret_cast<const float4*>(z + base);
    float4*       o4 = reinterpret_cast<float4*>(out + base);

    float4 vr[VEC_PER_THREAD];
    float4 zr[VEC_PER_THREAD];
    float dot = 0.0f;  // v·z partial
    float nsq = 0.0f;  // v·v partial

#pragma unroll
    for (int i = 0; i < VEC_PER_THREAD; ++i) {
        // stride-BLOCK layout: lane j reads vec (tid + i*BLOCK) → fully coalesced
        vr[i] = v4[tid + i * BLOCK];
        zr[i] = z4[tid + i * BLOCK];
        dot += vr[i].x * zr[i].x + vr[i].y * zr[i].y
             + vr[i].z * zr[i].z + vr[i].w * zr[i].w;
        nsq += vr[i].x * vr[i].x + vr[i].y * vr[i].y
             + vr[i].z * vr[i].z + vr[i].w * vr[i].w;
    }

    // wave-64 butterfly reduction
#pragma unroll
    for (int off = 32; off > 0; off >>= 1) {
        dot += __shfl_down(dot, off, 64);
        nsq += __shfl_down(nsq, off, 64);
    }

    // cross-wave reduction (4 waves per block)
    __shared__ float sdot[BLOCK / 64];
    __shared__ float snsq[BLOCK / 64];
    __shared__ float sscale;
    const int wave = tid >> 6;
    const int lane = tid & 63;
    if (lane == 0) {
        sdot[wave] = dot;
        snsq[wave] = nsq;
    }
    __syncthreads();
    if (tid == 0) {
        float d = 0.0f, n = 0.0f;
#pragma unroll
        for (int w = 0; w < BLOCK / 64; ++w) { d += sdot[w]; n += snsq[w]; }
        sscale = -2.0f * d / n;
    }
    __syncthreads();
    const float s = sscale;

#pragma unroll
    for (int i = 0; i < VEC_PER_THREAD; ++i) {
        float4 o;
        o.x = zr[i].x + s * vr[i].x;
        o.y = zr[i].y + s * vr[i].y;
        o.z = zr[i].z + s * vr[i].z;
        o.w = zr[i].w + s * vr[i].w;
        o4[tid + i * BLOCK] = o;
    }
}

extern "C" void kernel_launch(void* const* d_in, const int* in_sizes, int n_in,
                              void* d_out, int out_size, void* d_ws, size_t ws_size,
                              hipStream_t stream) {
    const float* v = (const float*)d_in[0];
    const float* z = (const float*)d_in[1];
    float* out = (float*)d_out;

    const int B = in_sizes[0] / L;  // 16384
    hh_kernel<<<B, BLOCK, 0, stream>>>(v, z, out);
}